// Round 2
// baseline (1058.555 us; speedup 1.0000x reference)
//
#include <hip/hip_runtime.h>

#define NN 100000
#define EE 1200000
#define NOUTF 64
#define NPG 75
#define GG 1334
#define BN_EPS 1e-5f

// ---- edge scatter for layer 1 (d=3) ----
__global__ void scatter1(const int* __restrict__ ei, const float* __restrict__ x,
                         float* __restrict__ agg) {
    int e = blockIdx.x * 256 + threadIdx.x;
    if (e >= EE) return;
    int s = ei[e];
    int d = ei[EE + e];
    atomicAdd(&agg[d * 3 + 0], x[s * 3 + 0]);
    atomicAdd(&agg[d * 3 + 1], x[s * 3 + 1]);
    atomicAdd(&agg[d * 3 + 2], x[s * 3 + 2]);
}

// ---- layer 1 node compute: in=3, out=64 ----
__global__ void layer1(const float* __restrict__ x, const float* __restrict__ agg,
                       const float* __restrict__ Wc, const float* __restrict__ bc,
                       const float* __restrict__ Wa, const float* __restrict__ ba,
                       const float* __restrict__ W1, const float* __restrict__ b1,
                       const float* __restrict__ W2, const float* __restrict__ b2,
                       float* __restrict__ out) {
    int t = blockIdx.x * 256 + threadIdx.x;       // N*64 threads
    if (t >= NN * NOUTF) return;
    int n = t >> 6, o = t & 63;
    float x0 = x[n * 3 + 0], x1 = x[n * 3 + 1], x2 = x[n * 3 + 2];
    float a0 = agg[n * 3 + 0], a1 = agg[n * 3 + 1], a2 = agg[n * 3 + 2];
    float lin = fmaf(x0, Wa[o], fmaf(x1, Wa[64 + o], fmaf(x2, Wa[128 + o], ba[o])));
    float cv  = fmaf(a0, Wc[o], fmaf(a1, Wc[64 + o], fmaf(a2, Wc[128 + o], bc[o])));
    float g1  = fmaf(x0, W1[o], fmaf(x1, W1[64 + o], fmaf(x2, W1[128 + o], b1[o])));
    float g2  = fmaf(x0, W2[o], fmaf(x1, W2[64 + o], fmaf(x2, W2[128 + o], b2[o])));
    float v = lin + cv + g1 * g2;
    out[t] = v > 0.0f ? v : 0.0f;
}

// ---- edge scatter for layers 2/3 (d=64): wave = one edge, lane = channel ----
__global__ void scatter64(const int* __restrict__ ei, const float* __restrict__ h,
                          float* __restrict__ agg) {
    int t = blockIdx.x * 256 + threadIdx.x;       // E*64 threads (76.8M, fits int)
    int e = t >> 6, o = t & 63;
    int s = ei[e];
    int d = ei[EE + e];
    atomicAdd(&agg[d * 64 + o], h[s * 64 + o]);
}

// ---- layers 2/3 node compute: 4 matvecs 64x64 + gated combine ----
__global__ __launch_bounds__(256) void layer23(
        const float* __restrict__ h, const float* __restrict__ agg,
        const float* __restrict__ Wc, const float* __restrict__ bc,
        const float* __restrict__ Wa, const float* __restrict__ ba,
        const float* __restrict__ W1, const float* __restrict__ b1,
        const float* __restrict__ W2, const float* __restrict__ b2,
        float* __restrict__ out) {
    __shared__ float hl[16][64];
    __shared__ float al[16][64];
    int n0 = blockIdx.x * 16;
    int tid = threadIdx.x;
    {   // cooperative stage: 16 rows of h and agg (1024 floats each) via float4
        const float4* hs = (const float4*)(h + (size_t)n0 * 64);
        const float4* as = (const float4*)(agg + (size_t)n0 * 64);
        ((float4*)&hl[0][0])[tid] = hs[tid];
        ((float4*)&al[0][0])[tid] = as[tid];
    }
    __syncthreads();
    int o = tid & 63;
    int q = tid >> 6;    // wave id 0..3; wave q handles nodes q*4..q*4+3
    float acc_a[4], acc_c[4], acc_1[4], acc_2[4];
#pragma unroll
    for (int k = 0; k < 4; k++) { acc_a[k] = 0; acc_c[k] = 0; acc_1[k] = 0; acc_2[k] = 0; }
#pragma unroll 8
    for (int i = 0; i < 64; i++) {
        float wa = Wa[i * 64 + o];
        float wc = Wc[i * 64 + o];
        float w1 = W1[i * 64 + o];
        float w2 = W2[i * 64 + o];
#pragma unroll
        for (int k = 0; k < 4; k++) {
            int m = q * 4 + k;
            float hv = hl[m][i];   // wave-uniform address -> LDS broadcast
            float av = al[m][i];
            acc_a[k] = fmaf(hv, wa, acc_a[k]);
            acc_c[k] = fmaf(av, wc, acc_c[k]);
            acc_1[k] = fmaf(hv, w1, acc_1[k]);
            acc_2[k] = fmaf(hv, w2, acc_2[k]);
        }
    }
    float bao = ba[o], bco = bc[o], b1o = b1[o], b2o = b2[o];
#pragma unroll
    for (int k = 0; k < 4; k++) {
        int m = q * 4 + k;
        float v = acc_a[k] + bao + acc_c[k] + bco + (acc_1[k] + b1o) * (acc_2[k] + b2o);
        out[(size_t)(n0 + m) * 64 + o] = v > 0.0f ? v : 0.0f;
    }
}

// ---- fused mean-pool + BN(eval) + MLP head + log_softmax; block = 1 graph ----
__global__ void pool_head(const float* __restrict__ h,
                          const float* __restrict__ gamma, const float* __restrict__ beta,
                          const float* __restrict__ mean, const float* __restrict__ var,
                          const float* __restrict__ Wf1, const float* __restrict__ bf1,
                          const float* __restrict__ Wf2, const float* __restrict__ bf2,
                          float* __restrict__ out) {
    __shared__ float z[64];
    __shared__ float hid[32];
    __shared__ float logit[10];
    int g = blockIdx.x, o = threadIdx.x;
    int n0 = g * NPG;
    int cnt = NN - n0; if (cnt > NPG) cnt = NPG;
    float s = 0.0f;
    for (int k = 0; k < cnt; k++) s += h[(size_t)(n0 + k) * 64 + o];
    s /= (float)cnt;
    z[o] = (s - mean[o]) * rsqrtf(var[o] + BN_EPS) * gamma[o] + beta[o];
    __syncthreads();
    if (o < 32) {
        float a = bf1[o];
#pragma unroll
        for (int i = 0; i < 64; i++) a = fmaf(z[i], Wf1[i * 32 + o], a);
        hid[o] = a > 0.0f ? a : 0.0f;
    }
    __syncthreads();
    if (o < 10) {
        float a = bf2[o];
#pragma unroll
        for (int j = 0; j < 32; j++) a = fmaf(hid[j], Wf2[j * 10 + o], a);
        logit[o] = a;
    }
    __syncthreads();
    if (o < 10) {
        float m = logit[0];
        for (int c = 1; c < 10; c++) m = fmaxf(m, logit[c]);
        float se = 0.0f;
        for (int c = 0; c < 10; c++) se += expf(logit[c] - m);
        out[g * 10 + o] = logit[o] - m - logf(se);
    }
}

extern "C" void kernel_launch(void* const* d_in, const int* in_sizes, int n_in,
                              void* d_out, int out_size, void* d_ws, size_t ws_size,
                              hipStream_t stream) {
    const float* x  = (const float*)d_in[0];
    const int*  ei  = (const int*)d_in[1];
    // d_in[2] = batch (unused: graphs are contiguous blocks of 75)
    const float *Wc1 = (const float*)d_in[3],  *bc1 = (const float*)d_in[4];
    const float *W11 = (const float*)d_in[5],  *b11 = (const float*)d_in[6];
    const float *W12 = (const float*)d_in[7],  *b12 = (const float*)d_in[8];
    const float *W13 = (const float*)d_in[9],  *b13 = (const float*)d_in[10];
    const float *Wc2 = (const float*)d_in[11], *bc2 = (const float*)d_in[12];
    const float *W21 = (const float*)d_in[13], *b21 = (const float*)d_in[14];
    const float *W22 = (const float*)d_in[15], *b22 = (const float*)d_in[16];
    const float *W23 = (const float*)d_in[17], *b23 = (const float*)d_in[18];
    const float *Wc3 = (const float*)d_in[19], *bc3 = (const float*)d_in[20];
    const float *W31 = (const float*)d_in[21], *b31 = (const float*)d_in[22];
    const float *W32 = (const float*)d_in[23], *b32 = (const float*)d_in[24];
    const float *W33 = (const float*)d_in[25], *b33 = (const float*)d_in[26];
    const float *bng = (const float*)d_in[27], *bnb = (const float*)d_in[28];
    const float *bnm = (const float*)d_in[29], *bnv = (const float*)d_in[30];
    const float *Wf1 = (const float*)d_in[31], *bf1 = (const float*)d_in[32];
    const float *Wf2 = (const float*)d_in[33], *bf2 = (const float*)d_in[34];
    float* out = (float*)d_out;

    float* hA  = (float*)d_ws;                      // N*64 fp32
    float* agg = hA + (size_t)NN * 64;              // N*64 fp32 (also holds N*3 agg1)
    float* hB  = agg + (size_t)NN * 64;             // N*64 fp32

    // layer 1
    hipMemsetAsync(agg, 0, (size_t)NN * 3 * sizeof(float), stream);
    scatter1<<<(EE + 255) / 256, 256, 0, stream>>>(ei, x, agg);
    layer1<<<(NN * NOUTF) / 256, 256, 0, stream>>>(x, agg, Wc1, bc1, W11, b11,
                                                   W12, b12, W13, b13, hA);
    // layer 2
    hipMemsetAsync(agg, 0, (size_t)NN * 64 * sizeof(float), stream);
    scatter64<<<(EE * 64) / 256, 256, 0, stream>>>(ei, hA, agg);
    layer23<<<NN / 16, 256, 0, stream>>>(hA, agg, Wc2, bc2, W21, b21,
                                         W22, b22, W23, b23, hB);
    // layer 3
    hipMemsetAsync(agg, 0, (size_t)NN * 64 * sizeof(float), stream);
    scatter64<<<(EE * 64) / 256, 256, 0, stream>>>(ei, hB, agg);
    layer23<<<NN / 16, 256, 0, stream>>>(hB, agg, Wc3, bc3, W31, b31,
                                         W32, b32, W33, b33, hA);
    // pool + BN + head
    pool_head<<<GG, 64, 0, stream>>>(hA, bng, bnb, bnm, bnv, Wf1, bf1, Wf2, bf2, out);
}

// Round 3
// 730.441 us; speedup vs baseline: 1.4492x; 1.4492x over previous
//
#include <hip/hip_runtime.h>

#define NN 100000
#define EE 1200000
#define NOUTF 64
#define NPG 75
#define GG 1334
#define BN_EPS 1e-5f
#define NBLK 391   // ceil(NN/256)

// ================= CSR build =================
__global__ void hist_kernel(const int* __restrict__ ei, int* __restrict__ deg) {
    int e = blockIdx.x * 256 + threadIdx.x;
    if (e >= EE) return;
    atomicAdd(&deg[ei[EE + e]], 1);
}

// block-local exclusive scan; block totals to bsum
__global__ void scan_block(const int* __restrict__ deg, int* __restrict__ row,
                           int* __restrict__ bsum) {
    __shared__ int tmp[256];
    int tid = threadIdx.x;
    int i = blockIdx.x * 256 + tid;
    int v = (i < NN) ? deg[i] : 0;
    tmp[tid] = v;
    __syncthreads();
    for (int off = 1; off < 256; off <<= 1) {
        int t = (tid >= off) ? tmp[tid - off] : 0;
        __syncthreads();
        tmp[tid] += t;
        __syncthreads();
    }
    if (i < NN) row[i] = tmp[tid] - v;            // exclusive within block
    if (tid == 255) bsum[blockIdx.x] = tmp[255];  // block total
}

// scan the 391 block totals (one block of 512)
__global__ void scan_bsums(const int* __restrict__ bsum, int* __restrict__ boff) {
    __shared__ int tmp[512];
    int tid = threadIdx.x;
    int v = (tid < NBLK) ? bsum[tid] : 0;
    tmp[tid] = v;
    __syncthreads();
    for (int off = 1; off < 512; off <<= 1) {
        int t = (tid >= off) ? tmp[tid - off] : 0;
        __syncthreads();
        tmp[tid] += t;
        __syncthreads();
    }
    if (tid < NBLK) boff[tid] = tmp[tid] - v;     // exclusive block offsets
}

// globalize row offsets; also init cursor = row; row[NN] = EE
__global__ void add_off(int* __restrict__ row, const int* __restrict__ boff,
                        int* __restrict__ cursor) {
    int i = blockIdx.x * 256 + threadIdx.x;
    if (i < NN) {
        int r = row[i] + boff[blockIdx.x];
        row[i] = r;
        cursor[i] = r;
    }
    if (i == 0) row[NN] = EE;
}

__global__ void fill_kernel(const int* __restrict__ ei, int* __restrict__ cursor,
                            int* __restrict__ csr) {
    int e = blockIdx.x * 256 + threadIdx.x;
    if (e >= EE) return;
    int d = ei[EE + e];
    int p = atomicAdd(&cursor[d], 1);
    csr[p] = ei[e];
}

// ================= layer 1 (d=3) =================
__global__ void gather3(const int* __restrict__ row, const int* __restrict__ csr,
                        const float* __restrict__ x, float* __restrict__ agg) {
    int n = blockIdx.x * 256 + threadIdx.x;
    if (n >= NN) return;
    int j0 = row[n], j1 = row[n + 1];
    float a0 = 0, a1 = 0, a2 = 0;
    for (int j = j0; j < j1; j++) {
        int s = csr[j];
        a0 += x[s * 3 + 0];
        a1 += x[s * 3 + 1];
        a2 += x[s * 3 + 2];
    }
    agg[n * 3 + 0] = a0; agg[n * 3 + 1] = a1; agg[n * 3 + 2] = a2;
}

__global__ void layer1(const float* __restrict__ x, const float* __restrict__ agg,
                       const float* __restrict__ Wc, const float* __restrict__ bc,
                       const float* __restrict__ Wa, const float* __restrict__ ba,
                       const float* __restrict__ W1, const float* __restrict__ b1,
                       const float* __restrict__ W2, const float* __restrict__ b2,
                       float* __restrict__ out) {
    int t = blockIdx.x * 256 + threadIdx.x;
    if (t >= NN * NOUTF) return;
    int n = t >> 6, o = t & 63;
    float x0 = x[n * 3 + 0], x1 = x[n * 3 + 1], x2 = x[n * 3 + 2];
    float a0 = agg[n * 3 + 0], a1 = agg[n * 3 + 1], a2 = agg[n * 3 + 2];
    float lin = fmaf(x0, Wa[o], fmaf(x1, Wa[64 + o], fmaf(x2, Wa[128 + o], ba[o])));
    float cv  = fmaf(a0, Wc[o], fmaf(a1, Wc[64 + o], fmaf(a2, Wc[128 + o], bc[o])));
    float g1  = fmaf(x0, W1[o], fmaf(x1, W1[64 + o], fmaf(x2, W1[128 + o], b1[o])));
    float g2  = fmaf(x0, W2[o], fmaf(x1, W2[64 + o], fmaf(x2, W2[128 + o], b2[o])));
    float v = lin + cv + g1 * g2;
    out[t] = v > 0.0f ? v : 0.0f;
}

// ================= aggregation by gather (d=64): wave = node, lane = channel ====
__global__ __launch_bounds__(256) void gather64(
        const int* __restrict__ row, const int* __restrict__ csr,
        const float* __restrict__ h, float* __restrict__ agg) {
    int n = blockIdx.x * 4 + (threadIdx.x >> 6);
    int o = threadIdx.x & 63;
    int j0 = row[n], j1 = row[n + 1];
    float acc = 0.0f;
    for (int j = j0; j < j1; j++) {
        int s = csr[j];                       // wave-uniform -> broadcast
        acc += h[(size_t)s * 64 + o];         // coalesced 256B row
    }
    agg[(size_t)n * 64 + o] = acc;
}

// ================= layers 2/3 node compute (in-place safe) =================
__global__ __launch_bounds__(256) void layer23(
        const float* __restrict__ h, const float* __restrict__ agg,
        const float* __restrict__ Wc, const float* __restrict__ bc,
        const float* __restrict__ Wa, const float* __restrict__ ba,
        const float* __restrict__ W1, const float* __restrict__ b1,
        const float* __restrict__ W2, const float* __restrict__ b2,
        float* __restrict__ out) {
    __shared__ float hl[16][64];
    __shared__ float al[16][64];
    int n0 = blockIdx.x * 16;
    int tid = threadIdx.x;
    {
        const float4* hs = (const float4*)(h + (size_t)n0 * 64);
        const float4* as = (const float4*)(agg + (size_t)n0 * 64);
        ((float4*)&hl[0][0])[tid] = hs[tid];
        ((float4*)&al[0][0])[tid] = as[tid];
    }
    __syncthreads();
    int o = tid & 63;
    int q = tid >> 6;
    float acc_a[4], acc_c[4], acc_1[4], acc_2[4];
#pragma unroll
    for (int k = 0; k < 4; k++) { acc_a[k] = 0; acc_c[k] = 0; acc_1[k] = 0; acc_2[k] = 0; }
#pragma unroll 8
    for (int i = 0; i < 64; i++) {
        float wa = Wa[i * 64 + o];
        float wc = Wc[i * 64 + o];
        float w1 = W1[i * 64 + o];
        float w2 = W2[i * 64 + o];
#pragma unroll
        for (int k = 0; k < 4; k++) {
            int m = q * 4 + k;
            float hv = hl[m][i];
            float av = al[m][i];
            acc_a[k] = fmaf(hv, wa, acc_a[k]);
            acc_c[k] = fmaf(av, wc, acc_c[k]);
            acc_1[k] = fmaf(hv, w1, acc_1[k]);
            acc_2[k] = fmaf(hv, w2, acc_2[k]);
        }
    }
    float bao = ba[o], bco = bc[o], b1o = b1[o], b2o = b2[o];
#pragma unroll
    for (int k = 0; k < 4; k++) {
        int m = q * 4 + k;
        float v = acc_a[k] + bao + acc_c[k] + bco + (acc_1[k] + b1o) * (acc_2[k] + b2o);
        out[(size_t)(n0 + m) * 64 + o] = v > 0.0f ? v : 0.0f;
    }
}

// ================= pool + BN + head =================
__global__ void pool_head(const float* __restrict__ h,
                          const float* __restrict__ gamma, const float* __restrict__ beta,
                          const float* __restrict__ mean, const float* __restrict__ var,
                          const float* __restrict__ Wf1, const float* __restrict__ bf1,
                          const float* __restrict__ Wf2, const float* __restrict__ bf2,
                          float* __restrict__ out) {
    __shared__ float z[64];
    __shared__ float hid[32];
    __shared__ float logit[10];
    int g = blockIdx.x, o = threadIdx.x;
    int n0 = g * NPG;
    int cnt = NN - n0; if (cnt > NPG) cnt = NPG;
    float s = 0.0f;
    for (int k = 0; k < cnt; k++) s += h[(size_t)(n0 + k) * 64 + o];
    s /= (float)cnt;
    z[o] = (s - mean[o]) * rsqrtf(var[o] + BN_EPS) * gamma[o] + beta[o];
    __syncthreads();
    if (o < 32) {
        float a = bf1[o];
#pragma unroll
        for (int i = 0; i < 64; i++) a = fmaf(z[i], Wf1[i * 32 + o], a);
        hid[o] = a > 0.0f ? a : 0.0f;
    }
    __syncthreads();
    if (o < 10) {
        float a = bf2[o];
#pragma unroll
        for (int j = 0; j < 32; j++) a = fmaf(hid[j], Wf2[j * 10 + o], a);
        logit[o] = a;
    }
    __syncthreads();
    if (o < 10) {
        float m = logit[0];
        for (int c = 1; c < 10; c++) m = fmaxf(m, logit[c]);
        float se = 0.0f;
        for (int c = 0; c < 10; c++) se += expf(logit[c] - m);
        out[g * 10 + o] = logit[o] - m - logf(se);
    }
}

extern "C" void kernel_launch(void* const* d_in, const int* in_sizes, int n_in,
                              void* d_out, int out_size, void* d_ws, size_t ws_size,
                              hipStream_t stream) {
    const float* x  = (const float*)d_in[0];
    const int*  ei  = (const int*)d_in[1];
    const float *Wc1 = (const float*)d_in[3],  *bc1 = (const float*)d_in[4];
    const float *W11 = (const float*)d_in[5],  *b11 = (const float*)d_in[6];
    const float *W12 = (const float*)d_in[7],  *b12 = (const float*)d_in[8];
    const float *W13 = (const float*)d_in[9],  *b13 = (const float*)d_in[10];
    const float *Wc2 = (const float*)d_in[11], *bc2 = (const float*)d_in[12];
    const float *W21 = (const float*)d_in[13], *b21 = (const float*)d_in[14];
    const float *W22 = (const float*)d_in[15], *b22 = (const float*)d_in[16];
    const float *W23 = (const float*)d_in[17], *b23 = (const float*)d_in[18];
    const float *Wc3 = (const float*)d_in[19], *bc3 = (const float*)d_in[20];
    const float *W31 = (const float*)d_in[21], *b31 = (const float*)d_in[22];
    const float *W32 = (const float*)d_in[23], *b32 = (const float*)d_in[24];
    const float *W33 = (const float*)d_in[25], *b33 = (const float*)d_in[26];
    const float *bng = (const float*)d_in[27], *bnb = (const float*)d_in[28];
    const float *bnm = (const float*)d_in[29], *bnv = (const float*)d_in[30];
    const float *Wf1 = (const float*)d_in[31], *bf1 = (const float*)d_in[32];
    const float *Wf2 = (const float*)d_in[33], *bf2 = (const float*)d_in[34];
    float* out = (float*)d_out;

    // workspace: hA | agg | row | cursor | bsum | boff | csr   (~57 MB)
    float* hA  = (float*)d_ws;                       // NN*64 f32
    float* agg = hA + (size_t)NN * 64;               // NN*64 f32 (first NN*3 = agg3)
    int* row    = (int*)(agg + (size_t)NN * 64);     // NN+1
    int* cursor = row + (NN + 2);                    // NN   (deg during build)
    int* bsum   = cursor + NN;                       // 512
    int* boff   = bsum + 512;                        // 512
    int* csr    = boff + 512;                        // EE

    int* deg = cursor;  // alias: deg lives where cursor will live

    // ---- CSR build (once per launch; graph fixed) ----
    hipMemsetAsync(deg, 0, (size_t)NN * sizeof(int), stream);
    hist_kernel<<<(EE + 255) / 256, 256, 0, stream>>>(ei, deg);
    scan_block<<<NBLK, 256, 0, stream>>>(deg, row, bsum);
    scan_bsums<<<1, 512, 0, stream>>>(bsum, boff);
    add_off<<<NBLK, 256, 0, stream>>>(row, boff, cursor);
    fill_kernel<<<(EE + 255) / 256, 256, 0, stream>>>(ei, cursor, csr);

    // ---- layer 1 ----
    gather3<<<NBLK, 256, 0, stream>>>(row, csr, x, agg);
    layer1<<<(NN * NOUTF) / 256, 256, 0, stream>>>(x, agg, Wc1, bc1, W11, b11,
                                                   W12, b12, W13, b13, hA);
    // ---- layer 2 (layer23 in-place: block writes only rows it staged) ----
    gather64<<<NN / 4, 256, 0, stream>>>(row, csr, hA, agg);
    layer23<<<NN / 16, 256, 0, stream>>>(hA, agg, Wc2, bc2, W21, b21,
                                         W22, b22, W23, b23, hA);
    // ---- layer 3 ----
    gather64<<<NN / 4, 256, 0, stream>>>(row, csr, hA, agg);
    layer23<<<NN / 16, 256, 0, stream>>>(hA, agg, Wc3, bc3, W31, b31,
                                         W32, b32, W33, b33, hA);
    // ---- pool + BN + head ----
    pool_head<<<GG, 64, 0, stream>>>(hA, bng, bnb, bnm, bnv, Wf1, bf1, Wf2, bf2, out);
}

// Round 9
// 584.346 us; speedup vs baseline: 1.8115x; 1.2500x over previous
//
#include <hip/hip_runtime.h>

#define NN 100000
#define EE 1200000
#define NOUTF 64
#define NPG 75
#define GG 1334
#define BN_EPS 1e-5f
#define NBLK 391   // ceil(NN/256)

// ================= CSR build =================
__global__ void hist_kernel(const int* __restrict__ ei, int* __restrict__ deg) {
    int e = blockIdx.x * 256 + threadIdx.x;
    if (e >= EE) return;
    atomicAdd(&deg[ei[EE + e]], 1);
}

__global__ void scan_block(const int* __restrict__ deg, int* __restrict__ row,
                           int* __restrict__ bsum) {
    __shared__ int tmp[256];
    int tid = threadIdx.x;
    int i = blockIdx.x * 256 + tid;
    int v = (i < NN) ? deg[i] : 0;
    tmp[tid] = v;
    __syncthreads();
    for (int off = 1; off < 256; off <<= 1) {
        int t = (tid >= off) ? tmp[tid - off] : 0;
        __syncthreads();
        tmp[tid] += t;
        __syncthreads();
    }
    if (i < NN) row[i] = tmp[tid] - v;
    if (tid == 255) bsum[blockIdx.x] = tmp[255];
}

__global__ void scan_bsums(const int* __restrict__ bsum, int* __restrict__ boff) {
    __shared__ int tmp[512];
    int tid = threadIdx.x;
    int v = (tid < NBLK) ? bsum[tid] : 0;
    tmp[tid] = v;
    __syncthreads();
    for (int off = 1; off < 512; off <<= 1) {
        int t = (tid >= off) ? tmp[tid - off] : 0;
        __syncthreads();
        tmp[tid] += t;
        __syncthreads();
    }
    if (tid < NBLK) boff[tid] = tmp[tid] - v;
}

__global__ void add_off(int* __restrict__ row, const int* __restrict__ boff,
                        int* __restrict__ cursor) {
    int i = blockIdx.x * 256 + threadIdx.x;
    if (i < NN) {
        int r = row[i] + boff[blockIdx.x];
        row[i] = r;
        cursor[i] = r;
    }
    if (i == 0) row[NN] = EE;
}

__global__ void fill_kernel(const int* __restrict__ ei, int* __restrict__ cursor,
                            int* __restrict__ csr) {
    int e = blockIdx.x * 256 + threadIdx.x;
    if (e >= EE) return;
    int d = ei[EE + e];
    int p = atomicAdd(&cursor[d], 1);
    csr[p] = ei[e];
}

// ================= layer 1 (d=3) =================
__global__ void gather3(const int* __restrict__ row, const int* __restrict__ csr,
                        const float* __restrict__ x, float* __restrict__ agg) {
    int n = blockIdx.x * 256 + threadIdx.x;
    if (n >= NN) return;
    int j0 = row[n], j1 = row[n + 1];
    float a0 = 0, a1 = 0, a2 = 0;
    int j = j0;
    for (; j + 4 <= j1; j += 4) {
        int s0 = csr[j], s1 = csr[j + 1], s2 = csr[j + 2], s3 = csr[j + 3];
        a0 += x[s0 * 3 + 0] + x[s1 * 3 + 0] + x[s2 * 3 + 0] + x[s3 * 3 + 0];
        a1 += x[s0 * 3 + 1] + x[s1 * 3 + 1] + x[s2 * 3 + 1] + x[s3 * 3 + 1];
        a2 += x[s0 * 3 + 2] + x[s1 * 3 + 2] + x[s2 * 3 + 2] + x[s3 * 3 + 2];
    }
    for (; j < j1; j++) {
        int s = csr[j];
        a0 += x[s * 3 + 0]; a1 += x[s * 3 + 1]; a2 += x[s * 3 + 2];
    }
    agg[n * 3 + 0] = a0; agg[n * 3 + 1] = a1; agg[n * 3 + 2] = a2;
}

__global__ void layer1(const float* __restrict__ x, const float* __restrict__ agg,
                       const float* __restrict__ Wc, const float* __restrict__ bc,
                       const float* __restrict__ Wa, const float* __restrict__ ba,
                       const float* __restrict__ W1, const float* __restrict__ b1,
                       const float* __restrict__ W2, const float* __restrict__ b2,
                       float* __restrict__ out) {
    int t = blockIdx.x * 256 + threadIdx.x;
    if (t >= NN * NOUTF) return;
    int n = t >> 6, o = t & 63;
    float x0 = x[n * 3 + 0], x1 = x[n * 3 + 1], x2 = x[n * 3 + 2];
    float a0 = agg[n * 3 + 0], a1 = agg[n * 3 + 1], a2 = agg[n * 3 + 2];
    float lin = fmaf(x0, Wa[o], fmaf(x1, Wa[64 + o], fmaf(x2, Wa[128 + o], ba[o])));
    float cv  = fmaf(a0, Wc[o], fmaf(a1, Wc[64 + o], fmaf(a2, Wc[128 + o], bc[o])));
    float g1  = fmaf(x0, W1[o], fmaf(x1, W1[64 + o], fmaf(x2, W1[128 + o], b1[o])));
    float g2  = fmaf(x0, W2[o], fmaf(x1, W2[64 + o], fmaf(x2, W2[128 + o], b2[o])));
    float v = lin + cv + g1 * g2;
    out[t] = v > 0.0f ? v : 0.0f;
}

// ======== fused aggregation + node compute for layers 2/3 ========
// Block = 16 nodes, 4 waves. Phase 1: stage own h rows + gather agg into LDS
// (wave = node, lane = channel, ILP-4 over edges). Phase 2: 4 matvecs.
// Reads h (random rows) / writes out -> MUST be different buffers.
__global__ __launch_bounds__(256) void aggl23(
        const int* __restrict__ row, const int* __restrict__ csr,
        const float* __restrict__ h,
        const float* __restrict__ Wc, const float* __restrict__ bc,
        const float* __restrict__ Wa, const float* __restrict__ ba,
        const float* __restrict__ W1, const float* __restrict__ b1,
        const float* __restrict__ W2, const float* __restrict__ b2,
        float* __restrict__ out) {
    __shared__ float hl[16][64];
    __shared__ float al[16][64];
    int n0 = blockIdx.x * 16;
    int tid = threadIdx.x;
    int o = tid & 63;
    int q = tid >> 6;      // wave id

    // stage own 16 h rows (contiguous, float4)
    ((float4*)&hl[0][0])[tid] = ((const float4*)(h + (size_t)n0 * 64))[tid];

    // gather: wave q handles nodes q*4..q*4+3; 4-edge ILP
#pragma unroll
    for (int k = 0; k < 4; k++) {
        int n = n0 + q * 4 + k;
        int j0 = row[n], j1 = row[n + 1];
        float acc = 0.0f;
        int j = j0;
        for (; j + 4 <= j1; j += 4) {
            int s0 = csr[j], s1 = csr[j + 1], s2 = csr[j + 2], s3 = csr[j + 3];
            float v0 = h[(size_t)s0 * 64 + o];
            float v1 = h[(size_t)s1 * 64 + o];
            float v2 = h[(size_t)s2 * 64 + o];
            float v3 = h[(size_t)s3 * 64 + o];
            acc += (v0 + v1) + (v2 + v3);
        }
        for (; j < j1; j++) acc += h[(size_t)csr[j] * 64 + o];
        al[q * 4 + k][o] = acc;
    }
    __syncthreads();

    // matvec phase: wave q computes output rows q*4..q*4+3, lane = out channel o
    float acc_a[4], acc_c[4], acc_1[4], acc_2[4];
#pragma unroll
    for (int k = 0; k < 4; k++) { acc_a[k] = 0; acc_c[k] = 0; acc_1[k] = 0; acc_2[k] = 0; }
#pragma unroll
    for (int i = 0; i < 64; i += 4) {
        float wa[4], wc[4], w1[4], w2[4];
#pragma unroll
        for (int r = 0; r < 4; r++) {
            wa[r] = Wa[(i + r) * 64 + o];
            wc[r] = Wc[(i + r) * 64 + o];
            w1[r] = W1[(i + r) * 64 + o];
            w2[r] = W2[(i + r) * 64 + o];
        }
#pragma unroll
        for (int k = 0; k < 4; k++) {
            int m = q * 4 + k;
            float4 hv = *(const float4*)&hl[m][i];   // wave-uniform -> LDS broadcast
            float4 av = *(const float4*)&al[m][i];
            acc_a[k] = fmaf(hv.w, wa[3], fmaf(hv.z, wa[2], fmaf(hv.y, wa[1], fmaf(hv.x, wa[0], acc_a[k]))));
            acc_c[k] = fmaf(av.w, wc[3], fmaf(av.z, wc[2], fmaf(av.y, wc[1], fmaf(av.x, wc[0], acc_c[k]))));
            acc_1[k] = fmaf(hv.w, w1[3], fmaf(hv.z, w1[2], fmaf(hv.y, w1[1], fmaf(hv.x, w1[0], acc_1[k]))));
            acc_2[k] = fmaf(hv.w, w2[3], fmaf(hv.z, w2[2], fmaf(hv.y, w2[1], fmaf(hv.x, w2[0], acc_2[k]))));
        }
    }
    float bao = ba[o], bco = bc[o], b1o = b1[o], b2o = b2[o];
#pragma unroll
    for (int k = 0; k < 4; k++) {
        int m = q * 4 + k;
        float v = acc_a[k] + bao + acc_c[k] + bco + (acc_1[k] + b1o) * (acc_2[k] + b2o);
        out[(size_t)(n0 + m) * 64 + o] = v > 0.0f ? v : 0.0f;
    }
}

// ================= pool + BN + head (256 threads / graph) =================
__global__ __launch_bounds__(256) void pool_head(
        const float* __restrict__ h,
        const float* __restrict__ gamma, const float* __restrict__ beta,
        const float* __restrict__ mean, const float* __restrict__ var,
        const float* __restrict__ Wf1, const float* __restrict__ bf1,
        const float* __restrict__ Wf2, const float* __restrict__ bf2,
        float* __restrict__ out) {
    __shared__ float part[4][64];
    __shared__ float z[64];
    __shared__ float hid[32];
    __shared__ float logit[10];
    int g = blockIdx.x;
    int tid = threadIdx.x;
    int o = tid & 63, w = tid >> 6;
    int n0 = g * NPG;
    int cnt = NN - n0; if (cnt > NPG) cnt = NPG;
    float s = 0.0f;
    for (int k = w; k < cnt; k += 4) s += h[(size_t)(n0 + k) * 64 + o];
    part[w][o] = s;
    __syncthreads();
    if (tid < 64) {
        float t = (part[0][o] + part[1][o]) + (part[2][o] + part[3][o]);
        t /= (float)cnt;
        z[o] = (t - mean[o]) * rsqrtf(var[o] + BN_EPS) * gamma[o] + beta[o];
    }
    __syncthreads();
    if (tid < 32) {
        float a = bf1[tid];
#pragma unroll
        for (int i = 0; i < 64; i++) a = fmaf(z[i], Wf1[i * 32 + tid], a);
        hid[tid] = a > 0.0f ? a : 0.0f;
    }
    __syncthreads();
    if (tid < 10) {
        float a = bf2[tid];
#pragma unroll
        for (int j = 0; j < 32; j++) a = fmaf(hid[j], Wf2[j * 10 + tid], a);
        logit[tid] = a;
    }
    __syncthreads();
    if (tid < 10) {
        float m = logit[0];
        for (int c = 1; c < 10; c++) m = fmaxf(m, logit[c]);
        float se = 0.0f;
        for (int c = 0; c < 10; c++) se += expf(logit[c] - m);
        out[g * 10 + tid] = logit[tid] - m - logf(se);
    }
}

extern "C" void kernel_launch(void* const* d_in, const int* in_sizes, int n_in,
                              void* d_out, int out_size, void* d_ws, size_t ws_size,
                              hipStream_t stream) {
    const float* x  = (const float*)d_in[0];
    const int*  ei  = (const int*)d_in[1];
    const float *Wc1 = (const float*)d_in[3],  *bc1 = (const float*)d_in[4];
    const float *W11 = (const float*)d_in[5],  *b11 = (const float*)d_in[6];
    const float *W12 = (const float*)d_in[7],  *b12 = (const float*)d_in[8];
    const float *W13 = (const float*)d_in[9],  *b13 = (const float*)d_in[10];
    const float *Wc2 = (const float*)d_in[11], *bc2 = (const float*)d_in[12];
    const float *W21 = (const float*)d_in[13], *b21 = (const float*)d_in[14];
    const float *W22 = (const float*)d_in[15], *b22 = (const float*)d_in[16];
    const float *W23 = (const float*)d_in[17], *b23 = (const float*)d_in[18];
    const float *Wc3 = (const float*)d_in[19], *bc3 = (const float*)d_in[20];
    const float *W31 = (const float*)d_in[21], *b31 = (const float*)d_in[22];
    const float *W32 = (const float*)d_in[23], *b32 = (const float*)d_in[24];
    const float *W33 = (const float*)d_in[25], *b33 = (const float*)d_in[26];
    const float *bng = (const float*)d_in[27], *bnb = (const float*)d_in[28];
    const float *bnm = (const float*)d_in[29], *bnv = (const float*)d_in[30];
    const float *Wf1 = (const float*)d_in[31], *bf1 = (const float*)d_in[32];
    const float *Wf2 = (const float*)d_in[33], *bf2 = (const float*)d_in[34];
    float* out = (float*)d_out;

    // workspace: hA | hB | row | cursor | bsum | boff | csr  (~57 MB)
    float* hA  = (float*)d_ws;                       // NN*64 f32
    float* hB  = hA + (size_t)NN * 64;               // NN*64 f32 (first NN*3 = agg3)
    int* row    = (int*)(hB + (size_t)NN * 64);      // NN+2
    int* cursor = row + (NN + 2);                    // NN (deg during build)
    int* bsum   = cursor + NN;                       // 512
    int* boff   = bsum + 512;                        // 512
    int* csr    = boff + 512;                        // EE

    int* deg = cursor;

    // ---- CSR build ----
    hipMemsetAsync(deg, 0, (size_t)NN * sizeof(int), stream);
    hist_kernel<<<(EE + 255) / 256, 256, 0, stream>>>(ei, deg);
    scan_block<<<NBLK, 256, 0, stream>>>(deg, row, bsum);
    scan_bsums<<<1, 512, 0, stream>>>(bsum, boff);
    add_off<<<NBLK, 256, 0, stream>>>(row, boff, cursor);
    fill_kernel<<<(EE + 255) / 256, 256, 0, stream>>>(ei, cursor, csr);

    // ---- layer 1: agg3 in hB scratch, h1 -> hA ----
    gather3<<<NBLK, 256, 0, stream>>>(row, csr, x, hB);
    layer1<<<(NN * NOUTF) / 256, 256, 0, stream>>>(x, hB, Wc1, bc1, W11, b11,
                                                   W12, b12, W13, b13, hA);
    // ---- layer 2: hA -> hB (fused gather+compute) ----
    aggl23<<<NN / 16, 256, 0, stream>>>(row, csr, hA, Wc2, bc2, W21, b21,
                                        W22, b22, W23, b23, hB);
    // ---- layer 3: hB -> hA ----
    aggl23<<<NN / 16, 256, 0, stream>>>(row, csr, hB, Wc3, bc3, W31, b31,
                                        W32, b32, W33, b33, hA);
    // ---- pool + BN + head ----
    pool_head<<<GG, 256, 0, stream>>>(hA, bng, bnb, bnm, bnv, Wf1, bf1, Wf2, bf2, out);
}

// Round 16
// 559.905 us; speedup vs baseline: 1.8906x; 1.0437x over previous
//
#include <hip/hip_runtime.h>

#define NN 100000
#define EE 1200000
#define NOUTF 64
#define NPG 75
#define GG 1334
#define BN_EPS 1e-5f
#define NBLK 391   // ceil(NN/256)

// ================= CSR build =================
__global__ void hist_kernel(const int* __restrict__ ei, int* __restrict__ deg) {
    int e = blockIdx.x * 256 + threadIdx.x;
    if (e >= EE) return;
    atomicAdd(&deg[ei[EE + e]], 1);
}

__global__ void scan_block(const int* __restrict__ deg, int* __restrict__ row,
                           int* __restrict__ bsum) {
    __shared__ int tmp[256];
    int tid = threadIdx.x;
    int i = blockIdx.x * 256 + tid;
    int v = (i < NN) ? deg[i] : 0;
    tmp[tid] = v;
    __syncthreads();
    for (int off = 1; off < 256; off <<= 1) {
        int t = (tid >= off) ? tmp[tid - off] : 0;
        __syncthreads();
        tmp[tid] += t;
        __syncthreads();
    }
    if (i < NN) row[i] = tmp[tid] - v;
    if (tid == 255) bsum[blockIdx.x] = tmp[255];
}

__global__ void scan_bsums(const int* __restrict__ bsum, int* __restrict__ boff) {
    __shared__ int tmp[512];
    int tid = threadIdx.x;
    int v = (tid < NBLK) ? bsum[tid] : 0;
    tmp[tid] = v;
    __syncthreads();
    for (int off = 1; off < 512; off <<= 1) {
        int t = (tid >= off) ? tmp[tid - off] : 0;
        __syncthreads();
        tmp[tid] += t;
        __syncthreads();
    }
    if (tid < NBLK) boff[tid] = tmp[tid] - v;
}

__global__ void add_off(int* __restrict__ row, const int* __restrict__ boff,
                        int* __restrict__ cursor) {
    int i = blockIdx.x * 256 + threadIdx.x;
    if (i < NN) {
        int r = row[i] + boff[blockIdx.x];
        row[i] = r;
        cursor[i] = r;
    }
    if (i == 0) row[NN] = EE;
}

__global__ void fill_kernel(const int* __restrict__ ei, int* __restrict__ cursor,
                            int* __restrict__ csr) {
    int e = blockIdx.x * 256 + threadIdx.x;
    if (e >= EE) return;
    int d = ei[EE + e];
    int p = atomicAdd(&cursor[d], 1);
    csr[p] = ei[e];
}

// ================= layer 1 (d=3) =================
__global__ void gather3(const int* __restrict__ row, const int* __restrict__ csr,
                        const float* __restrict__ x, float* __restrict__ agg) {
    int n = blockIdx.x * 256 + threadIdx.x;
    if (n >= NN) return;
    int j0 = row[n], j1 = row[n + 1];
    float a0 = 0, a1 = 0, a2 = 0;
    int j = j0;
    for (; j + 4 <= j1; j += 4) {
        int s0 = csr[j], s1 = csr[j + 1], s2 = csr[j + 2], s3 = csr[j + 3];
        a0 += x[s0 * 3 + 0] + x[s1 * 3 + 0] + x[s2 * 3 + 0] + x[s3 * 3 + 0];
        a1 += x[s0 * 3 + 1] + x[s1 * 3 + 1] + x[s2 * 3 + 1] + x[s3 * 3 + 1];
        a2 += x[s0 * 3 + 2] + x[s1 * 3 + 2] + x[s2 * 3 + 2] + x[s3 * 3 + 2];
    }
    for (; j < j1; j++) {
        int s = csr[j];
        a0 += x[s * 3 + 0]; a1 += x[s * 3 + 1]; a2 += x[s * 3 + 2];
    }
    agg[n * 3 + 0] = a0; agg[n * 3 + 1] = a1; agg[n * 3 + 2] = a2;
}

__global__ void layer1(const float* __restrict__ x, const float* __restrict__ agg,
                       const float* __restrict__ Wc, const float* __restrict__ bc,
                       const float* __restrict__ Wa, const float* __restrict__ ba,
                       const float* __restrict__ W1, const float* __restrict__ b1,
                       const float* __restrict__ W2, const float* __restrict__ b2,
                       float* __restrict__ out) {
    int t = blockIdx.x * 256 + threadIdx.x;
    if (t >= NN * NOUTF) return;
    int n = t >> 6, o = t & 63;
    float x0 = x[n * 3 + 0], x1 = x[n * 3 + 1], x2 = x[n * 3 + 2];
    float a0 = agg[n * 3 + 0], a1 = agg[n * 3 + 1], a2 = agg[n * 3 + 2];
    float lin = fmaf(x0, Wa[o], fmaf(x1, Wa[64 + o], fmaf(x2, Wa[128 + o], ba[o])));
    float cv  = fmaf(a0, Wc[o], fmaf(a1, Wc[64 + o], fmaf(a2, Wc[128 + o], bc[o])));
    float g1  = fmaf(x0, W1[o], fmaf(x1, W1[64 + o], fmaf(x2, W1[128 + o], b1[o])));
    float g2  = fmaf(x0, W2[o], fmaf(x1, W2[64 + o], fmaf(x2, W2[128 + o], b2[o])));
    float v = lin + cv + g1 * g2;
    out[t] = v > 0.0f ? v : 0.0f;
}

// ======== fused aggregation + node compute for layers 2/3 (v2) ========
// Block = 32 nodes, 4 waves (wave = 8 nodes).
// Gather: lane l = {edge-group g=l>>4, channels 4*(l&15)..+3}; 4 edges per
// wave-issue, unroll-2 -> 8 edges (2KB) in flight. Group-reduce via shfl_xor.
// Matvec: 8 nodes/wave amortizes weight loads; float4 LDS broadcast reads.
__global__ __launch_bounds__(256) void aggl23(
        const int* __restrict__ row, const int* __restrict__ csr,
        const float* __restrict__ h,
        const float* __restrict__ Wc, const float* __restrict__ bc,
        const float* __restrict__ Wa, const float* __restrict__ ba,
        const float* __restrict__ W1, const float* __restrict__ b1,
        const float* __restrict__ W2, const float* __restrict__ b2,
        float* __restrict__ out) {
    __shared__ float hl[32][64];
    __shared__ float al[32][64];
    int n0 = blockIdx.x * 32;
    int tid = threadIdx.x;
    int q = tid >> 6;        // wave 0..3
    int l = tid & 63;        // lane
    int g = l >> 4;          // edge group 0..3
    int c4 = (l & 15) * 4;   // channel base for gather

    // stage own 32 h rows (2048 float4, 8 per thread, coalesced)
    {
        const float4* hs = (const float4*)(h + (size_t)n0 * 64);
        float4* hld = (float4*)&hl[0][0];
#pragma unroll
        for (int r = 0; r < 8; r++) hld[tid + 256 * r] = hs[tid + 256 * r];
    }

    // gather: wave q owns nodes q*8..q*8+7
#pragma unroll 1
    for (int k = 0; k < 8; k++) {
        int n = n0 + q * 8 + k;
        int j0 = row[n], j1 = row[n + 1];
        float4 acc = make_float4(0.f, 0.f, 0.f, 0.f);
        int j = j0;
        for (; j + 8 <= j1; j += 8) {         // 8 edges in flight
            int sA = csr[j + g];
            int sB = csr[j + 4 + g];
            float4 vA = *(const float4*)(h + (size_t)sA * 64 + c4);
            float4 vB = *(const float4*)(h + (size_t)sB * 64 + c4);
            acc.x += vA.x + vB.x; acc.y += vA.y + vB.y;
            acc.z += vA.z + vB.z; acc.w += vA.w + vB.w;
        }
        for (; j < j1; j += 4) {              // tail: up to 4 edges, guarded
            int jj = j + g;
            if (jj < j1) {
                int s = csr[jj];
                float4 v = *(const float4*)(h + (size_t)s * 64 + c4);
                acc.x += v.x; acc.y += v.y; acc.z += v.z; acc.w += v.w;
            }
        }
        // reduce across the 4 edge-groups (lanes l, l^16, l^32, l^48)
        acc.x += __shfl_xor(acc.x, 16); acc.y += __shfl_xor(acc.y, 16);
        acc.z += __shfl_xor(acc.z, 16); acc.w += __shfl_xor(acc.w, 16);
        acc.x += __shfl_xor(acc.x, 32); acc.y += __shfl_xor(acc.y, 32);
        acc.z += __shfl_xor(acc.z, 32); acc.w += __shfl_xor(acc.w, 32);
        if (g == 0) *(float4*)&al[q * 8 + k][c4] = acc;
    }
    __syncthreads();

    // matvec: wave q computes rows q*8..q*8+7, lane = out channel o
    int o = l;
    float acc_a[8], acc_c[8], acc_1[8], acc_2[8];
#pragma unroll
    for (int k = 0; k < 8; k++) { acc_a[k] = 0; acc_c[k] = 0; acc_1[k] = 0; acc_2[k] = 0; }
#pragma unroll 4
    for (int i = 0; i < 64; i += 4) {
        float wa[4], wc[4], w1[4], w2[4];
#pragma unroll
        for (int r = 0; r < 4; r++) {
            wa[r] = Wa[(i + r) * 64 + o];
            wc[r] = Wc[(i + r) * 64 + o];
            w1[r] = W1[(i + r) * 64 + o];
            w2[r] = W2[(i + r) * 64 + o];
        }
#pragma unroll
        for (int k = 0; k < 8; k++) {
            int m = q * 8 + k;
            float4 hv = *(const float4*)&hl[m][i];   // wave-uniform -> broadcast
            float4 av = *(const float4*)&al[m][i];
            acc_a[k] = fmaf(hv.w, wa[3], fmaf(hv.z, wa[2], fmaf(hv.y, wa[1], fmaf(hv.x, wa[0], acc_a[k]))));
            acc_c[k] = fmaf(av.w, wc[3], fmaf(av.z, wc[2], fmaf(av.y, wc[1], fmaf(av.x, wc[0], acc_c[k]))));
            acc_1[k] = fmaf(hv.w, w1[3], fmaf(hv.z, w1[2], fmaf(hv.y, w1[1], fmaf(hv.x, w1[0], acc_1[k]))));
            acc_2[k] = fmaf(hv.w, w2[3], fmaf(hv.z, w2[2], fmaf(hv.y, w2[1], fmaf(hv.x, w2[0], acc_2[k]))));
        }
    }
    float bao = ba[o], bco = bc[o], b1o = b1[o], b2o = b2[o];
#pragma unroll
    for (int k = 0; k < 8; k++) {
        int m = q * 8 + k;
        float v = acc_a[k] + bao + acc_c[k] + bco + (acc_1[k] + b1o) * (acc_2[k] + b2o);
        out[(size_t)(n0 + m) * 64 + o] = v > 0.0f ? v : 0.0f;
    }
}

// ================= pool + BN + head (256 threads / graph) =================
__global__ __launch_bounds__(256) void pool_head(
        const float* __restrict__ h,
        const float* __restrict__ gamma, const float* __restrict__ beta,
        const float* __restrict__ mean, const float* __restrict__ var,
        const float* __restrict__ Wf1, const float* __restrict__ bf1,
        const float* __restrict__ Wf2, const float* __restrict__ bf2,
        float* __restrict__ out) {
    __shared__ float part[4][64];
    __shared__ float z[64];
    __shared__ float hid[32];
    __shared__ float logit[10];
    int g = blockIdx.x;
    int tid = threadIdx.x;
    int o = tid & 63, w = tid >> 6;
    int n0 = g * NPG;
    int cnt = NN - n0; if (cnt > NPG) cnt = NPG;
    float s = 0.0f;
    for (int k = w; k < cnt; k += 4) s += h[(size_t)(n0 + k) * 64 + o];
    part[w][o] = s;
    __syncthreads();
    if (tid < 64) {
        float t = (part[0][o] + part[1][o]) + (part[2][o] + part[3][o]);
        t /= (float)cnt;
        z[o] = (t - mean[o]) * rsqrtf(var[o] + BN_EPS) * gamma[o] + beta[o];
    }
    __syncthreads();
    if (tid < 32) {
        float a = bf1[tid];
#pragma unroll
        for (int i = 0; i < 64; i++) a = fmaf(z[i], Wf1[i * 32 + tid], a);
        hid[tid] = a > 0.0f ? a : 0.0f;
    }
    __syncthreads();
    if (tid < 10) {
        float a = bf2[tid];
#pragma unroll
        for (int j = 0; j < 32; j++) a = fmaf(hid[j], Wf2[j * 10 + tid], a);
        logit[tid] = a;
    }
    __syncthreads();
    if (tid < 10) {
        float m = logit[0];
        for (int c = 1; c < 10; c++) m = fmaxf(m, logit[c]);
        float se = 0.0f;
        for (int c = 0; c < 10; c++) se += expf(logit[c] - m);
        out[g * 10 + tid] = logit[tid] - m - logf(se);
    }
}

extern "C" void kernel_launch(void* const* d_in, const int* in_sizes, int n_in,
                              void* d_out, int out_size, void* d_ws, size_t ws_size,
                              hipStream_t stream) {
    const float* x  = (const float*)d_in[0];
    const int*  ei  = (const int*)d_in[1];
    const float *Wc1 = (const float*)d_in[3],  *bc1 = (const float*)d_in[4];
    const float *W11 = (const float*)d_in[5],  *b11 = (const float*)d_in[6];
    const float *W12 = (const float*)d_in[7],  *b12 = (const float*)d_in[8];
    const float *W13 = (const float*)d_in[9],  *b13 = (const float*)d_in[10];
    const float *Wc2 = (const float*)d_in[11], *bc2 = (const float*)d_in[12];
    const float *W21 = (const float*)d_in[13], *b21 = (const float*)d_in[14];
    const float *W22 = (const float*)d_in[15], *b22 = (const float*)d_in[16];
    const float *W23 = (const float*)d_in[17], *b23 = (const float*)d_in[18];
    const float *Wc3 = (const float*)d_in[19], *bc3 = (const float*)d_in[20];
    const float *W31 = (const float*)d_in[21], *b31 = (const float*)d_in[22];
    const float *W32 = (const float*)d_in[23], *b32 = (const float*)d_in[24];
    const float *W33 = (const float*)d_in[25], *b33 = (const float*)d_in[26];
    const float *bng = (const float*)d_in[27], *bnb = (const float*)d_in[28];
    const float *bnm = (const float*)d_in[29], *bnv = (const float*)d_in[30];
    const float *Wf1 = (const float*)d_in[31], *bf1 = (const float*)d_in[32];
    const float *Wf2 = (const float*)d_in[33], *bf2 = (const float*)d_in[34];
    float* out = (float*)d_out;

    // workspace: hA | hB | row | cursor | bsum | boff | csr  (~57 MB)
    float* hA  = (float*)d_ws;                       // NN*64 f32
    float* hB  = hA + (size_t)NN * 64;               // NN*64 f32 (first NN*3 = agg3)
    int* row    = (int*)(hB + (size_t)NN * 64);      // NN+2
    int* cursor = row + (NN + 2);                    // NN (deg during build)
    int* bsum   = cursor + NN;                       // 512
    int* boff   = bsum + 512;                        // 512
    int* csr    = boff + 512;                        // EE

    int* deg = cursor;

    // ---- CSR build ----
    hipMemsetAsync(deg, 0, (size_t)NN * sizeof(int), stream);
    hist_kernel<<<(EE + 255) / 256, 256, 0, stream>>>(ei, deg);
    scan_block<<<NBLK, 256, 0, stream>>>(deg, row, bsum);
    scan_bsums<<<1, 512, 0, stream>>>(bsum, boff);
    add_off<<<NBLK, 256, 0, stream>>>(row, boff, cursor);
    fill_kernel<<<(EE + 255) / 256, 256, 0, stream>>>(ei, cursor, csr);

    // ---- layer 1: agg3 in hB scratch, h1 -> hA ----
    gather3<<<NBLK, 256, 0, stream>>>(row, csr, x, hB);
    layer1<<<(NN * NOUTF) / 256, 256, 0, stream>>>(x, hB, Wc1, bc1, W11, b11,
                                                   W12, b12, W13, b13, hA);
    // ---- layer 2: hA -> hB (fused gather+compute, 32 nodes/block) ----
    aggl23<<<NN / 32, 256, 0, stream>>>(row, csr, hA, Wc2, bc2, W21, b21,
                                        W22, b22, W23, b23, hB);
    // ---- layer 3: hB -> hA ----
    aggl23<<<NN / 32, 256, 0, stream>>>(row, csr, hB, Wc3, bc3, W31, b31,
                                        W32, b32, W33, b33, hA);
    // ---- pool + BN + head ----
    pool_head<<<GG, 256, 0, stream>>>(hA, bng, bnb, bnm, bnv, Wf1, bf1, Wf2, bf2, out);
}

// Round 17
// 555.302 us; speedup vs baseline: 1.9063x; 1.0083x over previous
//
#include <hip/hip_runtime.h>

#define NN 100000
#define EE 1200000
#define NOUTF 64
#define NPG 75
#define GG 1334
#define BN_EPS 1e-5f
#define NBLK 391   // ceil(NN/256)

typedef unsigned short bf16_t;

__device__ __forceinline__ float bf2f(unsigned int u16) {
    return __uint_as_float(u16 << 16);
}
__device__ __forceinline__ bf16_t f2bf(float f) {
    unsigned int x = __float_as_uint(f);
    unsigned int r = (x + 0x7FFFu + ((x >> 16) & 1u)) >> 16;   // RNE
    return (bf16_t)r;
}

// ================= CSR build =================
__global__ void hist_kernel(const int* __restrict__ ei, int* __restrict__ deg) {
    int e = blockIdx.x * 256 + threadIdx.x;
    if (e >= EE) return;
    atomicAdd(&deg[ei[EE + e]], 1);
}

__global__ void scan_block(const int* __restrict__ deg, int* __restrict__ row,
                           int* __restrict__ bsum) {
    __shared__ int tmp[256];
    int tid = threadIdx.x;
    int i = blockIdx.x * 256 + tid;
    int v = (i < NN) ? deg[i] : 0;
    tmp[tid] = v;
    __syncthreads();
    for (int off = 1; off < 256; off <<= 1) {
        int t = (tid >= off) ? tmp[tid - off] : 0;
        __syncthreads();
        tmp[tid] += t;
        __syncthreads();
    }
    if (i < NN) row[i] = tmp[tid] - v;
    if (tid == 255) bsum[blockIdx.x] = tmp[255];
}

__global__ void scan_bsums(const int* __restrict__ bsum, int* __restrict__ boff) {
    __shared__ int tmp[512];
    int tid = threadIdx.x;
    int v = (tid < NBLK) ? bsum[tid] : 0;
    tmp[tid] = v;
    __syncthreads();
    for (int off = 1; off < 512; off <<= 1) {
        int t = (tid >= off) ? tmp[tid - off] : 0;
        __syncthreads();
        tmp[tid] += t;
        __syncthreads();
    }
    if (tid < NBLK) boff[tid] = tmp[tid] - v;
}

__global__ void add_off(int* __restrict__ row, const int* __restrict__ boff,
                        int* __restrict__ cursor) {
    int i = blockIdx.x * 256 + threadIdx.x;
    if (i < NN) {
        int r = row[i] + boff[blockIdx.x];
        row[i] = r;
        cursor[i] = r;
    }
    if (i == 0) row[NN] = EE;
}

__global__ void fill_kernel(const int* __restrict__ ei, int* __restrict__ cursor,
                            int* __restrict__ csr) {
    int e = blockIdx.x * 256 + threadIdx.x;
    if (e >= EE) return;
    int d = ei[EE + e];
    int p = atomicAdd(&cursor[d], 1);
    csr[p] = ei[e];
}

// ================= layer 1 (d=3) =================
__global__ void gather3(const int* __restrict__ row, const int* __restrict__ csr,
                        const float* __restrict__ x, float* __restrict__ agg) {
    int n = blockIdx.x * 256 + threadIdx.x;
    if (n >= NN) return;
    int j0 = row[n], j1 = row[n + 1];
    float a0 = 0, a1 = 0, a2 = 0;
    int j = j0;
    for (; j + 4 <= j1; j += 4) {
        int s0 = csr[j], s1 = csr[j + 1], s2 = csr[j + 2], s3 = csr[j + 3];
        a0 += x[s0 * 3 + 0] + x[s1 * 3 + 0] + x[s2 * 3 + 0] + x[s3 * 3 + 0];
        a1 += x[s0 * 3 + 1] + x[s1 * 3 + 1] + x[s2 * 3 + 1] + x[s3 * 3 + 1];
        a2 += x[s0 * 3 + 2] + x[s1 * 3 + 2] + x[s2 * 3 + 2] + x[s3 * 3 + 2];
    }
    for (; j < j1; j++) {
        int s = csr[j];
        a0 += x[s * 3 + 0]; a1 += x[s * 3 + 1]; a2 += x[s * 3 + 2];
    }
    agg[n * 3 + 0] = a0; agg[n * 3 + 1] = a1; agg[n * 3 + 2] = a2;
}

// writes h1 as bf16
__global__ void layer1(const float* __restrict__ x, const float* __restrict__ agg,
                       const float* __restrict__ Wc, const float* __restrict__ bc,
                       const float* __restrict__ Wa, const float* __restrict__ ba,
                       const float* __restrict__ W1, const float* __restrict__ b1,
                       const float* __restrict__ W2, const float* __restrict__ b2,
                       bf16_t* __restrict__ out) {
    int t = blockIdx.x * 256 + threadIdx.x;
    if (t >= NN * NOUTF) return;
    int n = t >> 6, o = t & 63;
    float x0 = x[n * 3 + 0], x1 = x[n * 3 + 1], x2 = x[n * 3 + 2];
    float a0 = agg[n * 3 + 0], a1 = agg[n * 3 + 1], a2 = agg[n * 3 + 2];
    float lin = fmaf(x0, Wa[o], fmaf(x1, Wa[64 + o], fmaf(x2, Wa[128 + o], ba[o])));
    float cv  = fmaf(a0, Wc[o], fmaf(a1, Wc[64 + o], fmaf(a2, Wc[128 + o], bc[o])));
    float g1  = fmaf(x0, W1[o], fmaf(x1, W1[64 + o], fmaf(x2, W1[128 + o], b1[o])));
    float g2  = fmaf(x0, W2[o], fmaf(x1, W2[64 + o], fmaf(x2, W2[128 + o], b2[o])));
    float v = lin + cv + g1 * g2;
    out[t] = f2bf(v > 0.0f ? v : 0.0f);
}

// ======== fused aggregation + node compute, bf16 h storage (v3) ========
// Structure identical to v2; h rows are bf16 (128B), gather loads 8B/lane.
// fp32 accumulation in registers + LDS; matvec phase unchanged (fp32 LDS).
__global__ __launch_bounds__(256) void aggl23(
        const int* __restrict__ row, const int* __restrict__ csr,
        const bf16_t* __restrict__ h,
        const float* __restrict__ Wc, const float* __restrict__ bc,
        const float* __restrict__ Wa, const float* __restrict__ ba,
        const float* __restrict__ W1, const float* __restrict__ b1,
        const float* __restrict__ W2, const float* __restrict__ b2,
        bf16_t* __restrict__ out) {
    __shared__ float hl[32][64];
    __shared__ float al[32][64];
    int n0 = blockIdx.x * 32;
    int tid = threadIdx.x;
    int q = tid >> 6;        // wave 0..3
    int l = tid & 63;        // lane
    int g = l >> 4;          // edge group 0..3
    int c4 = (l & 15) * 4;   // channel base (bf16 elements)

    // stage 32 bf16 rows (4KB) -> fp32 LDS; each thread: 8 bf16 via uint4
    {
        const uint4* hs = (const uint4*)(h + (size_t)n0 * 64);
        uint4 v = hs[tid];
        int base = tid * 8;
        float* dst = &hl[base >> 6][base & 63];   // 8 elems never cross a row
        dst[0] = bf2f(v.x & 0xFFFFu); dst[1] = bf2f(v.x >> 16);
        dst[2] = bf2f(v.y & 0xFFFFu); dst[3] = bf2f(v.y >> 16);
        dst[4] = bf2f(v.z & 0xFFFFu); dst[5] = bf2f(v.z >> 16);
        dst[6] = bf2f(v.w & 0xFFFFu); dst[7] = bf2f(v.w >> 16);
    }

    // gather: wave q owns nodes q*8..q*8+7; 8 edges in flight, 8B/lane
#pragma unroll 1
    for (int k = 0; k < 8; k++) {
        int n = n0 + q * 8 + k;
        int j0 = row[n], j1 = row[n + 1];
        float4 acc = make_float4(0.f, 0.f, 0.f, 0.f);
        int j = j0;
        for (; j + 8 <= j1; j += 8) {
            int sA = csr[j + g];
            int sB = csr[j + 4 + g];
            uint2 a = *(const uint2*)(h + (size_t)sA * 64 + c4);
            uint2 b = *(const uint2*)(h + (size_t)sB * 64 + c4);
            acc.x += bf2f(a.x & 0xFFFFu) + bf2f(b.x & 0xFFFFu);
            acc.y += bf2f(a.x >> 16)     + bf2f(b.x >> 16);
            acc.z += bf2f(a.y & 0xFFFFu) + bf2f(b.y & 0xFFFFu);
            acc.w += bf2f(a.y >> 16)     + bf2f(b.y >> 16);
        }
        for (; j < j1; j += 4) {              // tail, guarded
            int jj = j + g;
            if (jj < j1) {
                int s = csr[jj];
                uint2 a = *(const uint2*)(h + (size_t)s * 64 + c4);
                acc.x += bf2f(a.x & 0xFFFFu);
                acc.y += bf2f(a.x >> 16);
                acc.z += bf2f(a.y & 0xFFFFu);
                acc.w += bf2f(a.y >> 16);
            }
        }
        acc.x += __shfl_xor(acc.x, 16); acc.y += __shfl_xor(acc.y, 16);
        acc.z += __shfl_xor(acc.z, 16); acc.w += __shfl_xor(acc.w, 16);
        acc.x += __shfl_xor(acc.x, 32); acc.y += __shfl_xor(acc.y, 32);
        acc.z += __shfl_xor(acc.z, 32); acc.w += __shfl_xor(acc.w, 32);
        if (g == 0) *(float4*)&al[q * 8 + k][c4] = acc;
    }
    __syncthreads();

    // matvec: wave q computes rows q*8..q*8+7, lane = out channel o
    int o = l;
    float acc_a[8], acc_c[8], acc_1[8], acc_2[8];
#pragma unroll
    for (int k = 0; k < 8; k++) { acc_a[k] = 0; acc_c[k] = 0; acc_1[k] = 0; acc_2[k] = 0; }
#pragma unroll 4
    for (int i = 0; i < 64; i += 4) {
        float wa[4], wc[4], w1[4], w2[4];
#pragma unroll
        for (int r = 0; r < 4; r++) {
            wa[r] = Wa[(i + r) * 64 + o];
            wc[r] = Wc[(i + r) * 64 + o];
            w1[r] = W1[(i + r) * 64 + o];
            w2[r] = W2[(i + r) * 64 + o];
        }
#pragma unroll
        for (int k = 0; k < 8; k++) {
            int m = q * 8 + k;
            float4 hv = *(const float4*)&hl[m][i];   // wave-uniform -> broadcast
            float4 av = *(const float4*)&al[m][i];
            acc_a[k] = fmaf(hv.w, wa[3], fmaf(hv.z, wa[2], fmaf(hv.y, wa[1], fmaf(hv.x, wa[0], acc_a[k]))));
            acc_c[k] = fmaf(av.w, wc[3], fmaf(av.z, wc[2], fmaf(av.y, wc[1], fmaf(av.x, wc[0], acc_c[k]))));
            acc_1[k] = fmaf(hv.w, w1[3], fmaf(hv.z, w1[2], fmaf(hv.y, w1[1], fmaf(hv.x, w1[0], acc_1[k]))));
            acc_2[k] = fmaf(hv.w, w2[3], fmaf(hv.z, w2[2], fmaf(hv.y, w2[1], fmaf(hv.x, w2[0], acc_2[k]))));
        }
    }
    float bao = ba[o], bco = bc[o], b1o = b1[o], b2o = b2[o];
#pragma unroll
    for (int k = 0; k < 8; k++) {
        int m = q * 8 + k;
        float v = acc_a[k] + bao + acc_c[k] + bco + (acc_1[k] + b1o) * (acc_2[k] + b2o);
        out[(size_t)(n0 + m) * 64 + o] = f2bf(v > 0.0f ? v : 0.0f);
    }
}

// ================= pool + BN + head (256 threads / graph) =================
__global__ __launch_bounds__(256) void pool_head(
        const bf16_t* __restrict__ h,
        const float* __restrict__ gamma, const float* __restrict__ beta,
        const float* __restrict__ mean, const float* __restrict__ var,
        const float* __restrict__ Wf1, const float* __restrict__ bf1,
        const float* __restrict__ Wf2, const float* __restrict__ bf2,
        float* __restrict__ out) {
    __shared__ float part[4][64];
    __shared__ float z[64];
    __shared__ float hid[32];
    __shared__ float logit[10];
    int g = blockIdx.x;
    int tid = threadIdx.x;
    int o = tid & 63, w = tid >> 6;
    int n0 = g * NPG;
    int cnt = NN - n0; if (cnt > NPG) cnt = NPG;
    float s = 0.0f;
    for (int k = w; k < cnt; k += 4) s += bf2f(h[(size_t)(n0 + k) * 64 + o]);
    part[w][o] = s;
    __syncthreads();
    if (tid < 64) {
        float t = (part[0][o] + part[1][o]) + (part[2][o] + part[3][o]);
        t /= (float)cnt;
        z[o] = (t - mean[o]) * rsqrtf(var[o] + BN_EPS) * gamma[o] + beta[o];
    }
    __syncthreads();
    if (tid < 32) {
        float a = bf1[tid];
#pragma unroll
        for (int i = 0; i < 64; i++) a = fmaf(z[i], Wf1[i * 32 + tid], a);
        hid[tid] = a > 0.0f ? a : 0.0f;
    }
    __syncthreads();
    if (tid < 10) {
        float a = bf2[tid];
#pragma unroll
        for (int j = 0; j < 32; j++) a = fmaf(hid[j], Wf2[j * 10 + tid], a);
        logit[tid] = a;
    }
    __syncthreads();
    if (tid < 10) {
        float m = logit[0];
        for (int c = 1; c < 10; c++) m = fmaxf(m, logit[c]);
        float se = 0.0f;
        for (int c = 0; c < 10; c++) se += expf(logit[c] - m);
        out[g * 10 + tid] = logit[tid] - m - logf(se);
    }
}

extern "C" void kernel_launch(void* const* d_in, const int* in_sizes, int n_in,
                              void* d_out, int out_size, void* d_ws, size_t ws_size,
                              hipStream_t stream) {
    const float* x  = (const float*)d_in[0];
    const int*  ei  = (const int*)d_in[1];
    const float *Wc1 = (const float*)d_in[3],  *bc1 = (const float*)d_in[4];
    const float *W11 = (const float*)d_in[5],  *b11 = (const float*)d_in[6];
    const float *W12 = (const float*)d_in[7],  *b12 = (const float*)d_in[8];
    const float *W13 = (const float*)d_in[9],  *b13 = (const float*)d_in[10];
    const float *Wc2 = (const float*)d_in[11], *bc2 = (const float*)d_in[12];
    const float *W21 = (const float*)d_in[13], *b21 = (const float*)d_in[14];
    const float *W22 = (const float*)d_in[15], *b22 = (const float*)d_in[16];
    const float *W23 = (const float*)d_in[17], *b23 = (const float*)d_in[18];
    const float *Wc3 = (const float*)d_in[19], *bc3 = (const float*)d_in[20];
    const float *W31 = (const float*)d_in[21], *b31 = (const float*)d_in[22];
    const float *W32 = (const float*)d_in[23], *b32 = (const float*)d_in[24];
    const float *W33 = (const float*)d_in[25], *b33 = (const float*)d_in[26];
    const float *bng = (const float*)d_in[27], *bnb = (const float*)d_in[28];
    const float *bnm = (const float*)d_in[29], *bnv = (const float*)d_in[30];
    const float *Wf1 = (const float*)d_in[31], *bf1 = (const float*)d_in[32];
    const float *Wf2 = (const float*)d_in[33], *bf2 = (const float*)d_in[34];
    float* out = (float*)d_out;

    // workspace: hA(bf16) | hB(bf16) | agg3(f32) | row | cursor | bsum | boff | csr  (~32 MB)
    bf16_t* hA = (bf16_t*)d_ws;                      // NN*64 bf16
    bf16_t* hB = hA + (size_t)NN * 64;               // NN*64 bf16
    float* agg3 = (float*)(hB + (size_t)NN * 64);    // NN*3 f32
    int* row    = (int*)(agg3 + (size_t)NN * 3);     // NN+2
    int* cursor = row + (NN + 2);                    // NN (deg during build)
    int* bsum   = cursor + NN;                       // 512
    int* boff   = bsum + 512;                        // 512
    int* csr    = boff + 512;                        // EE

    int* deg = cursor;

    // ---- CSR build ----
    hipMemsetAsync(deg, 0, (size_t)NN * sizeof(int), stream);
    hist_kernel<<<(EE + 255) / 256, 256, 0, stream>>>(ei, deg);
    scan_block<<<NBLK, 256, 0, stream>>>(deg, row, bsum);
    scan_bsums<<<1, 512, 0, stream>>>(bsum, boff);
    add_off<<<NBLK, 256, 0, stream>>>(row, boff, cursor);
    fill_kernel<<<(EE + 255) / 256, 256, 0, stream>>>(ei, cursor, csr);

    // ---- layer 1: agg3 scratch, h1 -> hA (bf16) ----
    gather3<<<NBLK, 256, 0, stream>>>(row, csr, x, agg3);
    layer1<<<(NN * NOUTF) / 256, 256, 0, stream>>>(x, agg3, Wc1, bc1, W11, b11,
                                                   W12, b12, W13, b13, hA);
    // ---- layer 2: hA -> hB ----
    aggl23<<<NN / 32, 256, 0, stream>>>(row, csr, hA, Wc2, bc2, W21, b21,
                                        W22, b22, W23, b23, hB);
    // ---- layer 3: hB -> hA ----
    aggl23<<<NN / 32, 256, 0, stream>>>(row, csr, hB, Wc3, bc3, W31, b31,
                                        W32, b32, W33, b33, hA);
    // ---- pool + BN + head ----
    pool_head<<<GG, 256, 0, stream>>>(hA, bng, bnb, bnm, bnv, Wf1, bf1, Wf2, bf2, out);
}

// Round 18
// 468.573 us; speedup vs baseline: 2.2591x; 1.1851x over previous
//
#include <hip/hip_runtime.h>

#define NN 100000
#define EE 1200000
#define NOUTF 64
#define NPG 75
#define GG 1334
#define BN_EPS 1e-5f
#define NBLK 391   // ceil(NN/256)

typedef unsigned short bf16_t;

__device__ __forceinline__ float bf2f(unsigned int u16) {
    return __uint_as_float(u16 << 16);
}
__device__ __forceinline__ bf16_t f2bf(float f) {
    unsigned int x = __float_as_uint(f);
    unsigned int r = (x + 0x7FFFu + ((x >> 16) & 1u)) >> 16;   // RNE
    return (bf16_t)r;
}

// ================= CSR build =================
__global__ void hist_kernel(const int* __restrict__ ei, int* __restrict__ deg) {
    int e = blockIdx.x * 256 + threadIdx.x;
    if (e >= EE) return;
    atomicAdd(&deg[ei[EE + e]], 1);
}

__global__ void scan_block(const int* __restrict__ deg, int* __restrict__ row,
                           int* __restrict__ bsum) {
    __shared__ int tmp[256];
    int tid = threadIdx.x;
    int i = blockIdx.x * 256 + tid;
    int v = (i < NN) ? deg[i] : 0;
    tmp[tid] = v;
    __syncthreads();
    for (int off = 1; off < 256; off <<= 1) {
        int t = (tid >= off) ? tmp[tid - off] : 0;
        __syncthreads();
        tmp[tid] += t;
        __syncthreads();
    }
    if (i < NN) row[i] = tmp[tid] - v;
    if (tid == 255) bsum[blockIdx.x] = tmp[255];
}

__global__ void scan_bsums(const int* __restrict__ bsum, int* __restrict__ boff) {
    __shared__ int tmp[512];
    int tid = threadIdx.x;
    int v = (tid < NBLK) ? bsum[tid] : 0;
    tmp[tid] = v;
    __syncthreads();
    for (int off = 1; off < 512; off <<= 1) {
        int t = (tid >= off) ? tmp[tid - off] : 0;
        __syncthreads();
        tmp[tid] += t;
        __syncthreads();
    }
    if (tid < NBLK) boff[tid] = tmp[tid] - v;
}

__global__ void add_off(int* __restrict__ row, const int* __restrict__ boff,
                        int* __restrict__ cursor) {
    int i = blockIdx.x * 256 + threadIdx.x;
    if (i < NN) {
        int r = row[i] + boff[blockIdx.x];
        row[i] = r;
        cursor[i] = r;
    }
    if (i == 0) row[NN] = EE;
}

__global__ void fill_kernel(const int* __restrict__ ei, int* __restrict__ cursor,
                            int* __restrict__ csr) {
    int e = blockIdx.x * 256 + threadIdx.x;
    if (e >= EE) return;
    int d = ei[EE + e];
    int p = atomicAdd(&cursor[d], 1);
    csr[p] = ei[e];
}

// ================= layer 1 (d=3) =================
__global__ void gather3(const int* __restrict__ row, const int* __restrict__ csr,
                        const float* __restrict__ x, float* __restrict__ agg) {
    int n = blockIdx.x * 256 + threadIdx.x;
    if (n >= NN) return;
    int j0 = row[n], j1 = row[n + 1];
    float a0 = 0, a1 = 0, a2 = 0;
    int j = j0;
    for (; j + 4 <= j1; j += 4) {
        int s0 = csr[j], s1 = csr[j + 1], s2 = csr[j + 2], s3 = csr[j + 3];
        a0 += x[s0 * 3 + 0] + x[s1 * 3 + 0] + x[s2 * 3 + 0] + x[s3 * 3 + 0];
        a1 += x[s0 * 3 + 1] + x[s1 * 3 + 1] + x[s2 * 3 + 1] + x[s3 * 3 + 1];
        a2 += x[s0 * 3 + 2] + x[s1 * 3 + 2] + x[s2 * 3 + 2] + x[s3 * 3 + 2];
    }
    for (; j < j1; j++) {
        int s = csr[j];
        a0 += x[s * 3 + 0]; a1 += x[s * 3 + 1]; a2 += x[s * 3 + 2];
    }
    agg[n * 3 + 0] = a0; agg[n * 3 + 1] = a1; agg[n * 3 + 2] = a2;
}

// writes h1 as bf16
__global__ void layer1(const float* __restrict__ x, const float* __restrict__ agg,
                       const float* __restrict__ Wc, const float* __restrict__ bc,
                       const float* __restrict__ Wa, const float* __restrict__ ba,
                       const float* __restrict__ W1, const float* __restrict__ b1,
                       const float* __restrict__ W2, const float* __restrict__ b2,
                       bf16_t* __restrict__ out) {
    int t = blockIdx.x * 256 + threadIdx.x;
    if (t >= NN * NOUTF) return;
    int n = t >> 6, o = t & 63;
    float x0 = x[n * 3 + 0], x1 = x[n * 3 + 1], x2 = x[n * 3 + 2];
    float a0 = agg[n * 3 + 0], a1 = agg[n * 3 + 1], a2 = agg[n * 3 + 2];
    float lin = fmaf(x0, Wa[o], fmaf(x1, Wa[64 + o], fmaf(x2, Wa[128 + o], ba[o])));
    float cv  = fmaf(a0, Wc[o], fmaf(a1, Wc[64 + o], fmaf(a2, Wc[128 + o], bc[o])));
    float g1  = fmaf(x0, W1[o], fmaf(x1, W1[64 + o], fmaf(x2, W1[128 + o], b1[o])));
    float g2  = fmaf(x0, W2[o], fmaf(x1, W2[64 + o], fmaf(x2, W2[128 + o], b2[o])));
    float v = lin + cv + g1 * g2;
    out[t] = f2bf(v > 0.0f ? v : 0.0f);
}

// ======== fused aggregation + node compute, bf16 h, node-parallel gather (v4) ====
// Block = 32 nodes, 4 waves. Gather mapping: thread = {node l>>3, channels
// (l&7)*8..+7}. All 8 nodes of a wave run CONCURRENTLY in different lanes
// (v3 ran them serially -> 16 dependent memory rounds; that was the bound).
// Each thread loops its node's ~12 edges with 16B loads, unroll-2 -> 4 loads
// in flight. No shfl, no predication: thread owns its 8 channels, writes 2xfloat4.
__global__ __launch_bounds__(256) void aggl23(
        const int* __restrict__ row, const int* __restrict__ csr,
        const bf16_t* __restrict__ h,
        const float* __restrict__ Wc, const float* __restrict__ bc,
        const float* __restrict__ Wa, const float* __restrict__ ba,
        const float* __restrict__ W1, const float* __restrict__ b1,
        const float* __restrict__ W2, const float* __restrict__ b2,
        bf16_t* __restrict__ out) {
    __shared__ float hl[32][64];
    __shared__ float al[32][64];
    int n0 = blockIdx.x * 32;
    int tid = threadIdx.x;
    int q = tid >> 6;        // wave 0..3
    int l = tid & 63;        // lane

    // stage 32 bf16 rows (4KB) -> fp32 LDS; each thread: 8 bf16 via uint4
    {
        const uint4* hs = (const uint4*)(h + (size_t)n0 * 64);
        uint4 v = hs[tid];
        int base = tid * 8;
        float* dst = &hl[base >> 6][base & 63];   // 8 elems never cross a row
        dst[0] = bf2f(v.x & 0xFFFFu); dst[1] = bf2f(v.x >> 16);
        dst[2] = bf2f(v.y & 0xFFFFu); dst[3] = bf2f(v.y >> 16);
        dst[4] = bf2f(v.z & 0xFFFFu); dst[5] = bf2f(v.z >> 16);
        dst[6] = bf2f(v.w & 0xFFFFu); dst[7] = bf2f(v.w >> 16);
    }

    // gather: node-parallel. nd = wave-local node, cb = channel base (bf16 elems)
    {
        int nd = q * 8 + (l >> 3);
        int n  = n0 + nd;
        int cb = (l & 7) * 8;
        const bf16_t* hb = h + cb;
        float a0 = 0, a1 = 0, a2 = 0, a3 = 0, a4 = 0, a5 = 0, a6 = 0, a7 = 0;
        int j0 = row[n], j1 = row[n + 1];
        int j = j0;
#pragma unroll 2
        for (; j + 2 <= j1; j += 2) {
            int s0 = csr[j], s1 = csr[j + 1];
            uint4 v0 = *(const uint4*)(hb + (size_t)s0 * 64);
            uint4 v1 = *(const uint4*)(hb + (size_t)s1 * 64);
            a0 += bf2f(v0.x & 0xFFFFu) + bf2f(v1.x & 0xFFFFu);
            a1 += bf2f(v0.x >> 16)     + bf2f(v1.x >> 16);
            a2 += bf2f(v0.y & 0xFFFFu) + bf2f(v1.y & 0xFFFFu);
            a3 += bf2f(v0.y >> 16)     + bf2f(v1.y >> 16);
            a4 += bf2f(v0.z & 0xFFFFu) + bf2f(v1.z & 0xFFFFu);
            a5 += bf2f(v0.z >> 16)     + bf2f(v1.z >> 16);
            a6 += bf2f(v0.w & 0xFFFFu) + bf2f(v1.w & 0xFFFFu);
            a7 += bf2f(v0.w >> 16)     + bf2f(v1.w >> 16);
        }
        if (j < j1) {
            int s = csr[j];
            uint4 v = *(const uint4*)(hb + (size_t)s * 64);
            a0 += bf2f(v.x & 0xFFFFu); a1 += bf2f(v.x >> 16);
            a2 += bf2f(v.y & 0xFFFFu); a3 += bf2f(v.y >> 16);
            a4 += bf2f(v.z & 0xFFFFu); a5 += bf2f(v.z >> 16);
            a6 += bf2f(v.w & 0xFFFFu); a7 += bf2f(v.w >> 16);
        }
        *(float4*)&al[nd][cb]     = make_float4(a0, a1, a2, a3);
        *(float4*)&al[nd][cb + 4] = make_float4(a4, a5, a6, a7);
    }
    __syncthreads();

    // matvec: wave q computes rows q*8..q*8+7, lane = out channel o
    int o = l;
    float acc_a[8], acc_c[8], acc_1[8], acc_2[8];
#pragma unroll
    for (int k = 0; k < 8; k++) { acc_a[k] = 0; acc_c[k] = 0; acc_1[k] = 0; acc_2[k] = 0; }
#pragma unroll 4
    for (int i = 0; i < 64; i += 4) {
        float wa[4], wc[4], w1[4], w2[4];
#pragma unroll
        for (int r = 0; r < 4; r++) {
            wa[r] = Wa[(i + r) * 64 + o];
            wc[r] = Wc[(i + r) * 64 + o];
            w1[r] = W1[(i + r) * 64 + o];
            w2[r] = W2[(i + r) * 64 + o];
        }
#pragma unroll
        for (int k = 0; k < 8; k++) {
            int m = q * 8 + k;
            float4 hv = *(const float4*)&hl[m][i];   // wave-uniform -> broadcast
            float4 av = *(const float4*)&al[m][i];
            acc_a[k] = fmaf(hv.w, wa[3], fmaf(hv.z, wa[2], fmaf(hv.y, wa[1], fmaf(hv.x, wa[0], acc_a[k]))));
            acc_c[k] = fmaf(av.w, wc[3], fmaf(av.z, wc[2], fmaf(av.y, wc[1], fmaf(av.x, wc[0], acc_c[k]))));
            acc_1[k] = fmaf(hv.w, w1[3], fmaf(hv.z, w1[2], fmaf(hv.y, w1[1], fmaf(hv.x, w1[0], acc_1[k]))));
            acc_2[k] = fmaf(hv.w, w2[3], fmaf(hv.z, w2[2], fmaf(hv.y, w2[1], fmaf(hv.x, w2[0], acc_2[k]))));
        }
    }
    float bao = ba[o], bco = bc[o], b1o = b1[o], b2o = b2[o];
#pragma unroll
    for (int k = 0; k < 8; k++) {
        int m = q * 8 + k;
        float v = acc_a[k] + bao + acc_c[k] + bco + (acc_1[k] + b1o) * (acc_2[k] + b2o);
        out[(size_t)(n0 + m) * 64 + o] = f2bf(v > 0.0f ? v : 0.0f);
    }
}

// ================= pool + BN + head (256 threads / graph) =================
__global__ __launch_bounds__(256) void pool_head(
        const bf16_t* __restrict__ h,
        const float* __restrict__ gamma, const float* __restrict__ beta,
        const float* __restrict__ mean, const float* __restrict__ var,
        const float* __restrict__ Wf1, const float* __restrict__ bf1,
        const float* __restrict__ Wf2, const float* __restrict__ bf2,
        float* __restrict__ out) {
    __shared__ float part[4][64];
    __shared__ float z[64];
    __shared__ float hid[32];
    __shared__ float logit[10];
    int g = blockIdx.x;
    int tid = threadIdx.x;
    int o = tid & 63, w = tid >> 6;
    int n0 = g * NPG;
    int cnt = NN - n0; if (cnt > NPG) cnt = NPG;
    float s = 0.0f;
    for (int k = w; k < cnt; k += 4) s += bf2f(h[(size_t)(n0 + k) * 64 + o]);
    part[w][o] = s;
    __syncthreads();
    if (tid < 64) {
        float t = (part[0][o] + part[1][o]) + (part[2][o] + part[3][o]);
        t /= (float)cnt;
        z[o] = (t - mean[o]) * rsqrtf(var[o] + BN_EPS) * gamma[o] + beta[o];
    }
    __syncthreads();
    if (tid < 32) {
        float a = bf1[tid];
#pragma unroll
        for (int i = 0; i < 64; i++) a = fmaf(z[i], Wf1[i * 32 + tid], a);
        hid[tid] = a > 0.0f ? a : 0.0f;
    }
    __syncthreads();
    if (tid < 10) {
        float a = bf2[tid];
#pragma unroll
        for (int j = 0; j < 32; j++) a = fmaf(hid[j], Wf2[j * 10 + tid], a);
        logit[tid] = a;
    }
    __syncthreads();
    if (tid < 10) {
        float m = logit[0];
        for (int c = 1; c < 10; c++) m = fmaxf(m, logit[c]);
        float se = 0.0f;
        for (int c = 0; c < 10; c++) se += expf(logit[c] - m);
        out[g * 10 + tid] = logit[tid] - m - logf(se);
    }
}

extern "C" void kernel_launch(void* const* d_in, const int* in_sizes, int n_in,
                              void* d_out, int out_size, void* d_ws, size_t ws_size,
                              hipStream_t stream) {
    const float* x  = (const float*)d_in[0];
    const int*  ei  = (const int*)d_in[1];
    const float *Wc1 = (const float*)d_in[3],  *bc1 = (const float*)d_in[4];
    const float *W11 = (const float*)d_in[5],  *b11 = (const float*)d_in[6];
    const float *W12 = (const float*)d_in[7],  *b12 = (const float*)d_in[8];
    const float *W13 = (const float*)d_in[9],  *b13 = (const float*)d_in[10];
    const float *Wc2 = (const float*)d_in[11], *bc2 = (const float*)d_in[12];
    const float *W21 = (const float*)d_in[13], *b21 = (const float*)d_in[14];
    const float *W22 = (const float*)d_in[15], *b22 = (const float*)d_in[16];
    const float *W23 = (const float*)d_in[17], *b23 = (const float*)d_in[18];
    const float *Wc3 = (const float*)d_in[19], *bc3 = (const float*)d_in[20];
    const float *W31 = (const float*)d_in[21], *b31 = (const float*)d_in[22];
    const float *W32 = (const float*)d_in[23], *b32 = (const float*)d_in[24];
    const float *W33 = (const float*)d_in[25], *b33 = (const float*)d_in[26];
    const float *bng = (const float*)d_in[27], *bnb = (const float*)d_in[28];
    const float *bnm = (const float*)d_in[29], *bnv = (const float*)d_in[30];
    const float *Wf1 = (const float*)d_in[31], *bf1 = (const float*)d_in[32];
    const float *Wf2 = (const float*)d_in[33], *bf2 = (const float*)d_in[34];
    float* out = (float*)d_out;

    // workspace: hA(bf16) | hB(bf16) | agg3(f32) | row | cursor | bsum | boff | csr  (~32 MB)
    bf16_t* hA = (bf16_t*)d_ws;                      // NN*64 bf16
    bf16_t* hB = hA + (size_t)NN * 64;               // NN*64 bf16
    float* agg3 = (float*)(hB + (size_t)NN * 64);    // NN*3 f32
    int* row    = (int*)(agg3 + (size_t)NN * 3);     // NN+2
    int* cursor = row + (NN + 2);                    // NN (deg during build)
    int* bsum   = cursor + NN;                       // 512
    int* boff   = bsum + 512;                        // 512
    int* csr    = boff + 512;                        // EE

    int* deg = cursor;

    // ---- CSR build ----
    hipMemsetAsync(deg, 0, (size_t)NN * sizeof(int), stream);
    hist_kernel<<<(EE + 255) / 256, 256, 0, stream>>>(ei, deg);
    scan_block<<<NBLK, 256, 0, stream>>>(deg, row, bsum);
    scan_bsums<<<1, 512, 0, stream>>>(bsum, boff);
    add_off<<<NBLK, 256, 0, stream>>>(row, boff, cursor);
    fill_kernel<<<(EE + 255) / 256, 256, 0, stream>>>(ei, cursor, csr);

    // ---- layer 1: agg3 scratch, h1 -> hA (bf16) ----
    gather3<<<NBLK, 256, 0, stream>>>(row, csr, x, agg3);
    layer1<<<(NN * NOUTF) / 256, 256, 0, stream>>>(x, agg3, Wc1, bc1, W11, b11,
                                                   W12, b12, W13, b13, hA);
    // ---- layer 2: hA -> hB ----
    aggl23<<<NN / 32, 256, 0, stream>>>(row, csr, hA, Wc2, bc2, W21, b21,
                                        W22, b22, W23, b23, hB);
    // ---- layer 3: hB -> hA ----
    aggl23<<<NN / 32, 256, 0, stream>>>(row, csr, hB, Wc3, bc3, W31, b31,
                                        W32, b32, W33, b33, hA);
    // ---- pool + BN + head ----
    pool_head<<<GG, 256, 0, stream>>>(hA, bng, bnb, bnm, bnv, Wf1, bf1, Wf2, bf2, out);
}